// Round 15
// baseline (6162.280 us; speedup 1.0000x reference)
//
#include <hip/hip_runtime.h>
#include <hip/hip_bf16.h>

#define S_LEN 512
#define B_SZ  256
#define F_SZ  256
#define H_SZ  1024
#define BH    (B_SZ * H_SZ)
#define KEEP  0.5f

typedef float f32x4 __attribute__((ext_vector_type(4)));
typedef short s16x8 __attribute__((ext_vector_type(8)));
typedef int   i32x4 __attribute__((ext_vector_type(4)));

static __device__ __forceinline__ short f2bf(float f) {
    unsigned u = __builtin_bit_cast(unsigned, f);
    unsigned r = u + 0x7fffu + ((u >> 16) & 1u);   // RNE to bf16
    return (short)(r >> 16);
}

static __device__ __forceinline__ s16x8 pack8(f32x4 lo, f32x4 hi, float s) {
    s16x8 r;
#pragma unroll
    for (int i = 0; i < 4; ++i) { r[i] = f2bf(lo[i] * s); r[i + 4] = f2bf(hi[i] * s); }
    return r;
}

// packed converts (xi_gemm only — isolated kernel)
static __device__ __forceinline__ s16x8 pack8_pk(f32x4 lo, f32x4 hi) {
    int w0, w1, w2, w3;
    asm("v_cvt_pk_bf16_f32 %0, %1, %2" : "=v"(w0) : "v"(lo[0]), "v"(lo[1]));
    asm("v_cvt_pk_bf16_f32 %0, %1, %2" : "=v"(w1) : "v"(lo[2]), "v"(lo[3]));
    asm("v_cvt_pk_bf16_f32 %0, %1, %2" : "=v"(w2) : "v"(hi[0]), "v"(hi[1]));
    asm("v_cvt_pk_bf16_f32 %0, %1, %2" : "=v"(w3) : "v"(hi[2]), "v"(hi[3]));
    i32x4 r = { w0, w1, w2, w3 };
    return __builtin_bit_cast(s16x8, r);
}

static __device__ __forceinline__ long pack4_pk(f32x4 a) {
    int lo, hi;
    asm("v_cvt_pk_bf16_f32 %0, %1, %2" : "=v"(lo) : "v"(a[0]), "v"(a[1]));
    asm("v_cvt_pk_bf16_f32 %0, %1, %2" : "=v"(hi) : "v"(a[2]), "v"(a[3]));
    return (long)(((unsigned long)(unsigned)hi << 32) | (unsigned)lo);
}

static __device__ __forceinline__ f32x4 unpack4(long v) {
    unsigned lo = (unsigned)v, hi = (unsigned)((unsigned long)v >> 32);
    f32x4 r;
    r[0] = __builtin_bit_cast(float, lo << 16);
    r[1] = __builtin_bit_cast(float, lo & 0xffff0000u);
    r[2] = __builtin_bit_cast(float, hi << 16);
    r[3] = __builtin_bit_cast(float, hi & 0xffff0000u);
    return r;
}

static __device__ __forceinline__ float fast_tanh(float v) {
    float e = __expf(2.0f * v);
    return (e - 1.0f) / (e + 1.0f);
}

#define SYS_LD(p)   __hip_atomic_load((p), __ATOMIC_RELAXED, __HIP_MEMORY_SCOPE_SYSTEM)
#define SYS_ST(p,v) __hip_atomic_store((p), (v), __ATOMIC_RELAXED, __HIP_MEMORY_SCOPE_SYSTEM)
#define AGT_LD(p)   __hip_atomic_load((p), __ATOMIC_RELAXED, __HIP_MEMORY_SCOPE_AGENT)

// Flag atomics (R14-proven): PURE -> no sc1 (XCD-local TCC); mixed -> sc0 sc1.
template<int PURE>
static __device__ __forceinline__ int rmw_flag(int* p, int v) {
    int r;
    if constexpr (PURE)
        asm volatile("global_atomic_add %0, %1, %2, off sc0\n\ts_waitcnt vmcnt(0)"
                     : "=v"(r) : "v"(p), "v"(v) : "memory");
    else
        asm volatile("global_atomic_add %0, %1, %2, off sc0 sc1\n\ts_waitcnt vmcnt(0)"
                     : "=v"(r) : "v"(p), "v"(v) : "memory");
    return r;
}

template<int PURE>
static __device__ __forceinline__ void sig_flag(int* p) {
    int one = 1;
    if constexpr (PURE)
        asm volatile("global_atomic_add %0, %1, off" :: "v"(p), "v"(one) : "memory");
    else
        asm volatile("global_atomic_add %0, %1, off sc1" :: "v"(p), "v"(one) : "memory");
}

template<int PURE>
static __device__ __forceinline__ void sth(short* p, short v) {
    int vi = v;
    if constexpr (PURE)
        asm volatile("global_store_short %0, %1, off" :: "v"(p), "v"(vi) : "memory");
    else
        asm volatile("global_store_short %0, %1, off sc0 sc1" :: "v"(p), "v"(vi) : "memory");
}

#define MFMA(A, B, C) __builtin_amdgcn_mfma_f32_16x16x32_bf16((A), (B), (C), 0, 0, 0)

// ---------------- R14-proven coarse step loop (fallback paths) ----------------
template<int PURE, int XI>
static __device__ __forceinline__ void step_loop(
    const float* __restrict__ x, const float* __restrict__ h0,
    float* __restrict__ out, short* __restrict__ hbuf, int* __restrict__ flags,
    const char* __restrict__ xi_lane, char* h_lds,
    const s16x8 (&wh)[32], const s16x8 (&wif)[8], float bj,
    int g, int b0, int role, int j, int wIdx, int wave, int lane, int tid, int dmask)
{
    const int ln = lane & 15;
    const int lk = lane >> 4;
    const int arow = b0 + ln;
    const int crow = b0 + lk * 4;
    const int xr = (ln & 7) << 4;
    const int rbase = ln * 2048 + lk * 16;
    int* const inbox  = flags + role * 64;
    int* const fanout = flags + ((g * 16 + lane) * 64 + wIdx);

    long xv = 0;
    if constexpr (XI) xv = *(const long*)xi_lane;

#pragma unroll 1
    for (int s = 0; s < S_LEN; ++s) {
        f32x4 acc[4];
        acc[1] = f32x4{ 0.f, 0.f, 0.f, 0.f };
        acc[2] = f32x4{ 0.f, 0.f, 0.f, 0.f };
        acc[3] = f32x4{ 0.f, 0.f, 0.f, 0.f };

        if constexpr (!XI) {
            acc[0] = f32x4{ bj, bj, bj, bj };
            const float* xp = x + ((size_t)s * B_SZ + arow) * F_SZ + lk * 8;
#pragma unroll
            for (int kf = 0; kf < 8; ++kf) {
                s16x8 a = pack8(*(const f32x4*)(xp + kf * 32),
                                *(const f32x4*)(xp + kf * 32 + 4), 1.0f);
                acc[kf & 1] = MFMA(a, wif[kf], acc[kf & 1]);
            }
        }

        if (s > 0) {
            if (wave == 0) {
                int it = 0;
                for (;;) {
                    int v = rmw_flag<PURE>(inbox + lane, 0);
                    if (__all(v >= s)) break;
                    if (++it > (1 << 14)) break;
                    __builtin_amdgcn_s_sleep(1);
                }
            }
            __syncthreads();

            const char* slice = (const char*)(hbuf + (size_t)((s - 1) & dmask) * BH
                                              + (size_t)b0 * H_SZ);
            long o[16];
#pragma unroll
            for (int r = 0; r < 16; ++r) {
                const long* p = (const long*)(slice + r * 2048) + tid;
                o[r] = PURE ? AGT_LD(p) : SYS_LD(p);
            }
#pragma unroll
            for (int r = 0; r < 16; ++r)
                *(long*)(h_lds + ((r * 2048 + tid * 8) ^ ((r & 7) << 4))) = o[r];
            __syncthreads();
            if constexpr (XI) acc[0] = unpack4(xv);

#pragma unroll
            for (int ks = 0; ks < 32; ++ks) {
                s16x8 a = *(const s16x8*)(h_lds + ((rbase + ks * 64) ^ xr));
                acc[ks & 3] = MFMA(a, wh[ks], acc[ks & 3]);
            }
        } else {
            if constexpr (XI) acc[0] = unpack4(xv);
#pragma unroll
            for (int ks = 0; ks < 32; ++ks) {
                const float* p = h0 + ks * 32 + lk * 8;
                s16x8 a = pack8(*(const f32x4*)p, *(const f32x4*)(p + 4), KEEP);
                acc[ks & 3] = MFMA(a, wh[ks], acc[ks & 3]);
            }
        }

        f32x4 r4 = (acc[0] + acc[1]) + (acc[2] + acc[3]);

        if (s < S_LEN - 1) {
            short* op = hbuf + (size_t)(s & dmask) * BH;
#pragma unroll
            for (int r = 0; r < 4; ++r)
                sth<PURE>(op + (crow + r) * H_SZ + j, f2bf(KEEP * fast_tanh(r4[r])));
            asm volatile("s_waitcnt vmcnt(0)" ::: "memory");
            if (lane < 16) sig_flag<PURE>(fanout);
            if constexpr (XI)
                xv = *(const long*)(xi_lane + (size_t)(s + 1) * (256u * 4 * 64 * 8));
        } else {
#pragma unroll
            for (int r = 0; r < 4; ++r)
                out[(crow + r) * H_SZ + j] = fast_tanh(r4[r]);
        }
    }
}

// -------- fine-grained tile-pipelined step loop (PURE + XI only) --------
// h arrives as 16 independent 64-col tiles. Wave w stages tiles {w,w+4,w+8,
// w+12}: polls only that producer's 4 inbox slots (+ own WG's 4, so LDS isn't
// overwritten while own waves still read it — no cycle: own waves signal
// after consuming, never wait on our staging). Tiles announced via monotonic
// LDS flags; all waves consume in 4 chunks of 4 tiles. NO __syncthreads in
// the hot loop. Inter-WG protocol byte-identical to R14.
template<int XI>
static __device__ __forceinline__ void step_loop_fine(
    const float* __restrict__ h0, float* __restrict__ out,
    short* __restrict__ hbuf, int* __restrict__ flags,
    const char* __restrict__ xi_lane, char* h_lds,
    const s16x8 (&wh)[32],
    int g, int b0, int role, int t, int j, int wIdx, int wave, int lane, int tid,
    int dmask)
{
    const int ln = lane & 15;
    const int lk = lane >> 4;
    const int crow = b0 + lk * 4;
    volatile int* lflag = (volatile int*)(h_lds + 16 * 2048);
    int* const inbox  = flags + role * 64;
    int* const fanout = flags + ((g * 16 + lane) * 64 + wIdx);

    const int srow = lane & 15;     // staging row within the 16-row slice
    const int su   = lane >> 4;     // staging 8B-unit base (0..3)

    if (tid < 16) lflag[tid] = 0;
    __syncthreads();                // once, before the loop

    long xv = 0;
    if constexpr (XI) xv = *(const long*)xi_lane;

#pragma unroll 1
    for (int s = 0; s < S_LEN; ++s) {
        f32x4 acc[4];
        acc[1] = f32x4{ 0.f, 0.f, 0.f, 0.f };
        acc[2] = f32x4{ 0.f, 0.f, 0.f, 0.f };
        acc[3] = f32x4{ 0.f, 0.f, 0.f, 0.f };

        if (s > 0) {
            // ---- stage my 4 tiles as their producers arrive ----
            const char* slice = (const char*)(hbuf + (size_t)((s - 1) & dmask) * BH
                                              + (size_t)b0 * H_SZ);
#pragma unroll 1
            for (int i = 0; i < 4; ++i) {
                const int tp = wave + i * 4;
                // poll: lanes 0-3 producer tp's waves; lanes 4-7 own WG's waves
                int* sp = (lane < 4) ? (inbox + tp * 4 + lane)
                                     : (inbox + t * 4 + (lane & 3));
                int it = 0;
                for (;;) {
                    int v = (lane < 8) ? rmw_flag<1>(sp, 0) : s;
                    if (__all(v >= s)) break;
                    if (++it > (1 << 14)) break;      // watchdog: fail-visible
                    __builtin_amdgcn_s_sleep(1);
                }
                // stage tile tp (2KB): 4 x 8B per lane, swizzled LDS image
                const char* gb = slice + srow * 2048 + tp * 128;
                char* lb = h_lds + tp * 2048 + srow * 128;
                const int xw = (srow & 7) << 4;
#pragma unroll
                for (int q = 0; q < 4; ++q) {
                    const int u = su + q * 4;
                    long v = AGT_LD((const long*)(gb + u * 8));
                    *(long*)(lb + ((u * 8) ^ xw)) = v;
                }
                __threadfence_block();               // LDS data before flag
                if (lane == 0) lflag[tp] = s;
            }
            if constexpr (XI) acc[0] = unpack4(xv);

            // ---- consume in 4 chunks of 4 tiles (LDS-flag spin, no barrier) ----
#pragma unroll 1
            for (int c = 0; c < 4; ++c) {
                int it = 0;
                for (;;) {
                    int v = (lane < 4) ? lflag[c * 4 + lane] : s;
                    if (__all(v >= s)) break;
                    if (++it > (1 << 16)) break;      // watchdog: fail-visible
                }
#pragma unroll
                for (int t2 = 0; t2 < 4; ++t2) {
                    const int tile = c * 4 + t2;
                    const char* tb = h_lds + tile * 2048 + ln * 128;
                    const int xr = (ln & 7) << 4;
#pragma unroll
                    for (int half = 0; half < 2; ++half) {
                        const int ks = tile * 2 + half;
                        s16x8 a = *(const s16x8*)(tb + ((half * 64 + lk * 16) ^ xr));
                        acc[ks & 3] = MFMA(a, wh[ks], acc[ks & 3]);
                    }
                }
            }
        } else {
            if constexpr (XI) acc[0] = unpack4(xv);
            else acc[0] = f32x4{ 0.f, 0.f, 0.f, 0.f };
            // step 0: h0 broadcast across batch (same fragment for all rows)
#pragma unroll
            for (int ks = 0; ks < 32; ++ks) {
                const float* p = h0 + ks * 32 + lk * 8;
                s16x8 a = pack8(*(const f32x4*)p, *(const f32x4*)(p + 4), KEEP);
                acc[ks & 3] = MFMA(a, wh[ks], acc[ks & 3]);
            }
        }

        f32x4 r4 = (acc[0] + acc[1]) + (acc[2] + acc[3]);

        // producer tail — byte-identical to R14
        if (s < S_LEN - 1) {
            short* op = hbuf + (size_t)(s & dmask) * BH;
#pragma unroll
            for (int r = 0; r < 4; ++r)
                sth<1>(op + (crow + r) * H_SZ + j, f2bf(KEEP * fast_tanh(r4[r])));
            asm volatile("s_waitcnt vmcnt(0)" ::: "memory");
            if (lane < 16) sig_flag<1>(fanout);
            if constexpr (XI)
                xv = *(const long*)(xi_lane + (size_t)(s + 1) * (256u * 4 * 64 * 8));
        } else {
#pragma unroll
            for (int r = 0; r < 4; ++r)
                out[(crow + r) * H_SZ + j] = fast_tanh(r4[r]);
        }
    }
}

// ---------- kernel A: xi = x@Wi^T + b (sync-free; coalesced output) ----------
__global__ __launch_bounds__(256, 1) void xi_gemm(
    const float* __restrict__ x, const float* __restrict__ Wi,
    const float* __restrict__ bias, char* __restrict__ xi)
{
    const int bid  = blockIdx.x;
    const int role = bid & 255;
    const int c    = bid >> 8;
    const int tid  = threadIdx.x;
    const int wave = tid >> 6;
    const int lane = tid & 63;
    const int ln   = lane & 15;
    const int lk   = lane >> 4;

    const int b0    = (role >> 4) * 16;
    const int jtile = (role & 15) * 64;

    s16x8 wia[4][8];
    float b4[4];
#pragma unroll
    for (int jt = 0; jt < 4; ++jt) {
        b4[jt] = bias[jtile + jt * 16 + ln];
#pragma unroll
        for (int kf = 0; kf < 8; ++kf) {
            const float* p = Wi + (size_t)(jtile + jt * 16 + ln) * F_SZ
                           + kf * 32 + lk * 8;
            wia[jt][kf] = pack8_pk(*(const f32x4*)p, *(const f32x4*)(p + 4));
        }
    }

#pragma unroll 1
    for (int i = 0; i < 16; ++i) {
        const int s = c * 64 + wave + 4 * i;
        const float* xp = x + ((size_t)s * B_SZ + b0 + ln) * F_SZ + lk * 8;
        s16x8 af[8];
#pragma unroll
        for (int kf = 0; kf < 8; ++kf)
            af[kf] = pack8_pk(*(const f32x4*)(xp + kf * 32),
                              *(const f32x4*)(xp + kf * 32 + 4));
#pragma unroll
        for (int jt = 0; jt < 4; ++jt) {
            f32x4 a = { b4[jt], b4[jt], b4[jt], b4[jt] };
#pragma unroll
            for (int kf = 0; kf < 8; ++kf)
                a = MFMA(af[kf], wia[jt][kf], a);
            *(long*)(xi + ((((size_t)s * 256 + role) * 4 + jt) * 64 + lane) * 8)
                = pack4_pk(a);
        }
    }
}

// ---------- kernel B: recurrence ----------
template<int XI>
__global__ __launch_bounds__(256, 1) void rnn_fused(
    const float* __restrict__ x, const float* __restrict__ Wi,
    const float* __restrict__ bias, const float* __restrict__ Wh,
    const float* __restrict__ h0, float* __restrict__ out,
    short* __restrict__ hbuf, int* __restrict__ roster, int* __restrict__ flags,
    const char* __restrict__ xi, int dmask)
{
    __shared__ char h_lds[32768 + 64];   // 16 tiles x 2KB + 16 LDS flags
    __shared__ int sh_pure;
    const int bid  = blockIdx.x;
    const int role = ((bid & 7) << 5) | (bid >> 3);
    const int g    = role >> 4;
    const int t    = role & 15;
    const int tid  = threadIdx.x;
    const int wave = tid >> 6;
    const int lane = tid & 63;
    const int ln   = lane & 15;
    const int lk   = lane >> 4;

    int xcc;
    asm volatile("s_getreg_b32 %0, hwreg(HW_REG_XCC_ID)" : "=s"(xcc));
    xcc &= 7;

    if (tid == 0) SYS_ST(&roster[role], xcc + 1);
    if (tid < 16) {
        const int* rp = roster + g * 16 + tid;
        int v, it = 0;
        do { v = SYS_LD(rp); if (v) break; if (++it > (1 << 18)) break;
             __builtin_amdgcn_s_sleep(1); } while (1);
        int p = __all(v == __shfl(v, 0));
        if (tid == 0) sh_pure = p;
    }
    __syncthreads();
    const int pure = sh_pure;

    const int b0 = g * 16;
    const int j  = t * 64 + wave * 16 + ln;
    const int wIdx = t * 4 + wave;
    const char* xi_lane = xi + (((size_t)role * 4 + wave) * 64 + lane) * 8;

    s16x8 wh[32];
#pragma unroll
    for (int ks = 0; ks < 32; ++ks) {
        const float* p = Wh + (size_t)j * H_SZ + ks * 32 + lk * 8;
        wh[ks] = pack8(*(const f32x4*)p, *(const f32x4*)(p + 4), 1.0f);
    }
    s16x8 wif[8];
    if constexpr (!XI) {
#pragma unroll
        for (int kf = 0; kf < 8; ++kf) {
            const float* p = Wi + (size_t)j * F_SZ + kf * 32 + lk * 8;
            wif[kf] = pack8(*(const f32x4*)p, *(const f32x4*)(p + 4), 1.0f);
        }
    } else {
#pragma unroll
        for (int kf = 0; kf < 8; ++kf) wif[kf] = s16x8{0,0,0,0,0,0,0,0};
    }
    const float bj = XI ? 0.f : bias[j];

    if (pure && XI) {
        step_loop_fine<XI>(h0, out, hbuf, flags, xi_lane, h_lds, wh,
                           g, b0, role, t, j, wIdx, wave, lane, tid, dmask);
    } else if (pure) {
        step_loop<1, XI>(x, h0, out, hbuf, flags, xi_lane, h_lds, wh, wif, bj,
                         g, b0, role, j, wIdx, wave, lane, tid, dmask);
    } else {
        step_loop<0, XI>(x, h0, out, hbuf, flags, xi_lane, h_lds, wh, wif, bj,
                         g, b0, role, j, wIdx, wave, lane, tid, dmask);
    }
}

extern "C" void kernel_launch(void* const* d_in, const int* in_sizes, int n_in,
                              void* d_out, int out_size, void* d_ws, size_t ws_size,
                              hipStream_t stream) {
    const float* x  = (const float*)d_in[0];
    const float* Wi = (const float*)d_in[1];
    const float* bi = (const float*)d_in[2];
    const float* Wh = (const float*)d_in[3];
    const float* h0 = (const float*)d_in[4];
    float* out = (float*)d_out;

    int*   roster = (int*)d_ws;                          // 256 ints @ 0
    int*   flags  = (int*)((char*)d_ws + (4 << 10));     // 256 inboxes x 64 = 64KB
    short* hbuf   = (short*)((char*)d_ws + (128 << 10)); // depth x 512 KB bf16
    char*  xi     = (char*)d_ws + (128 << 10) + 4 * (size_t)BH * 2;

    const size_t need4   = (128u << 10) + 4 * (size_t)BH * 2;          // ~2.1 MB
    const size_t need_xi = need4 + (size_t)S_LEN * 256 * 4 * 64 * 8;   // ~270.7 MB

    const int dmask = (ws_size >= need4) ? 3 : 1;

    // roster + inboxes MUST be zero every call (graph replays don't re-poison)
    (void)hipMemsetAsync(d_ws, 0, (68 << 10), stream);

    if (ws_size >= need_xi) {
        xi_gemm<<<dim3(2048), dim3(256), 0, stream>>>(x, Wi, bi, xi);
        rnn_fused<1><<<dim3(256), dim3(256), 0, stream>>>(
            x, Wi, bi, Wh, h0, out, hbuf, roster, flags, xi, dmask);
    } else {
        rnn_fused<0><<<dim3(256), dim3(256), 0, stream>>>(
            x, Wi, bi, Wh, h0, out, hbuf, roster, flags, nullptr, dmask);
    }
}

// Round 16
// 3447.284 us; speedup vs baseline: 1.7876x; 1.7876x over previous
//
#include <hip/hip_runtime.h>
#include <hip/hip_bf16.h>

#define S_LEN 512
#define B_SZ  256
#define F_SZ  256
#define H_SZ  1024
#define BH    (B_SZ * H_SZ)
#define KEEP  0.5f

typedef float f32x4 __attribute__((ext_vector_type(4)));
typedef short s16x8 __attribute__((ext_vector_type(8)));
typedef int   i32x4 __attribute__((ext_vector_type(4)));

static __device__ __forceinline__ short f2bf(float f) {
    unsigned u = __builtin_bit_cast(unsigned, f);
    unsigned r = u + 0x7fffu + ((u >> 16) & 1u);   // RNE to bf16
    return (short)(r >> 16);
}

static __device__ __forceinline__ s16x8 pack8(f32x4 lo, f32x4 hi, float s) {
    s16x8 r;
#pragma unroll
    for (int i = 0; i < 4; ++i) { r[i] = f2bf(lo[i] * s); r[i + 4] = f2bf(hi[i] * s); }
    return r;
}

// packed converts (xi_gemm only — isolated kernel)
static __device__ __forceinline__ s16x8 pack8_pk(f32x4 lo, f32x4 hi) {
    int w0, w1, w2, w3;
    asm("v_cvt_pk_bf16_f32 %0, %1, %2" : "=v"(w0) : "v"(lo[0]), "v"(lo[1]));
    asm("v_cvt_pk_bf16_f32 %0, %1, %2" : "=v"(w1) : "v"(lo[2]), "v"(lo[3]));
    asm("v_cvt_pk_bf16_f32 %0, %1, %2" : "=v"(w2) : "v"(hi[0]), "v"(hi[1]));
    asm("v_cvt_pk_bf16_f32 %0, %1, %2" : "=v"(w3) : "v"(hi[2]), "v"(hi[3]));
    i32x4 r = { w0, w1, w2, w3 };
    return __builtin_bit_cast(s16x8, r);
}

static __device__ __forceinline__ long pack4_pk(f32x4 a) {
    int lo, hi;
    asm("v_cvt_pk_bf16_f32 %0, %1, %2" : "=v"(lo) : "v"(a[0]), "v"(a[1]));
    asm("v_cvt_pk_bf16_f32 %0, %1, %2" : "=v"(hi) : "v"(a[2]), "v"(a[3]));
    return (long)(((unsigned long)(unsigned)hi << 32) | (unsigned)lo);
}

static __device__ __forceinline__ f32x4 unpack4(long v) {
    unsigned lo = (unsigned)v, hi = (unsigned)((unsigned long)v >> 32);
    f32x4 r;
    r[0] = __builtin_bit_cast(float, lo << 16);
    r[1] = __builtin_bit_cast(float, lo & 0xffff0000u);
    r[2] = __builtin_bit_cast(float, hi << 16);
    r[3] = __builtin_bit_cast(float, hi & 0xffff0000u);
    return r;
}

static __device__ __forceinline__ float fast_tanh(float v) {
    float e = __expf(2.0f * v);
    return (e - 1.0f) / (e + 1.0f);
}

#define SYS_LD(p)   __hip_atomic_load((p), __ATOMIC_RELAXED, __HIP_MEMORY_SCOPE_SYSTEM)
#define SYS_ST(p,v) __hip_atomic_store((p), (v), __ATOMIC_RELAXED, __HIP_MEMORY_SCOPE_SYSTEM)
#define AGT_LD(p)   __hip_atomic_load((p), __ATOMIC_RELAXED, __HIP_MEMORY_SCOPE_AGENT)

// Flag atomics (R14-proven): PURE -> no sc1 (XCD-local TCC); mixed -> sc0 sc1.
template<int PURE>
static __device__ __forceinline__ int rmw_flag(int* p, int v) {
    int r;
    if constexpr (PURE)
        asm volatile("global_atomic_add %0, %1, %2, off sc0\n\ts_waitcnt vmcnt(0)"
                     : "=v"(r) : "v"(p), "v"(v) : "memory");
    else
        asm volatile("global_atomic_add %0, %1, %2, off sc0 sc1\n\ts_waitcnt vmcnt(0)"
                     : "=v"(r) : "v"(p), "v"(v) : "memory");
    return r;
}

template<int PURE>
static __device__ __forceinline__ void sig_flag(int* p) {
    int one = 1;
    if constexpr (PURE)
        asm volatile("global_atomic_add %0, %1, off" :: "v"(p), "v"(one) : "memory");
    else
        asm volatile("global_atomic_add %0, %1, off sc1" :: "v"(p), "v"(one) : "memory");
}

template<int PURE>
static __device__ __forceinline__ void sth(short* p, short v) {
    int vi = v;
    if constexpr (PURE)
        asm volatile("global_store_short %0, %1, off" :: "v"(p), "v"(vi) : "memory");
    else
        asm volatile("global_store_short %0, %1, off sc0 sc1" :: "v"(p), "v"(vi) : "memory");
}

#define MFMA(A, B, C) __builtin_amdgcn_mfma_f32_16x16x32_bf16((A), (B), (C), 0, 0, 0)

// ---------------- R14-proven coarse step loop (fallback paths) ----------------
template<int PURE, int XI>
static __device__ __forceinline__ void step_loop(
    const float* __restrict__ x, const float* __restrict__ h0,
    float* __restrict__ out, short* __restrict__ hbuf, int* __restrict__ flags,
    const char* __restrict__ xi_lane, char* h_lds,
    const s16x8 (&wh)[32], const s16x8 (&wif)[8], float bj,
    int g, int b0, int role, int j, int wIdx, int wave, int lane, int tid, int dmask)
{
    const int ln = lane & 15;
    const int lk = lane >> 4;
    const int arow = b0 + ln;
    const int crow = b0 + lk * 4;
    const int xr = (ln & 7) << 4;
    const int rbase = ln * 2048 + lk * 16;
    int* const inbox  = flags + role * 64;
    int* const fanout = flags + ((g * 16 + lane) * 64 + wIdx);

    long xv = 0;
    if constexpr (XI) xv = *(const long*)xi_lane;

#pragma unroll 1
    for (int s = 0; s < S_LEN; ++s) {
        f32x4 acc[4];
        acc[1] = f32x4{ 0.f, 0.f, 0.f, 0.f };
        acc[2] = f32x4{ 0.f, 0.f, 0.f, 0.f };
        acc[3] = f32x4{ 0.f, 0.f, 0.f, 0.f };

        if constexpr (!XI) {
            acc[0] = f32x4{ bj, bj, bj, bj };
            const float* xp = x + ((size_t)s * B_SZ + arow) * F_SZ + lk * 8;
#pragma unroll
            for (int kf = 0; kf < 8; ++kf) {
                s16x8 a = pack8(*(const f32x4*)(xp + kf * 32),
                                *(const f32x4*)(xp + kf * 32 + 4), 1.0f);
                acc[kf & 1] = MFMA(a, wif[kf], acc[kf & 1]);
            }
        }

        if (s > 0) {
            if (wave == 0) {
                int it = 0;
                for (;;) {
                    int v = rmw_flag<PURE>(inbox + lane, 0);
                    if (__all(v >= s)) break;
                    if (++it > (1 << 14)) break;
                    __builtin_amdgcn_s_sleep(1);
                }
            }
            __syncthreads();

            const char* slice = (const char*)(hbuf + (size_t)((s - 1) & dmask) * BH
                                              + (size_t)b0 * H_SZ);
            long o[16];
#pragma unroll
            for (int r = 0; r < 16; ++r) {
                const long* p = (const long*)(slice + r * 2048) + tid;
                o[r] = PURE ? AGT_LD(p) : SYS_LD(p);
            }
#pragma unroll
            for (int r = 0; r < 16; ++r)
                *(long*)(h_lds + ((r * 2048 + tid * 8) ^ ((r & 7) << 4))) = o[r];
            __syncthreads();
            if constexpr (XI) acc[0] = unpack4(xv);

#pragma unroll
            for (int ks = 0; ks < 32; ++ks) {
                s16x8 a = *(const s16x8*)(h_lds + ((rbase + ks * 64) ^ xr));
                acc[ks & 3] = MFMA(a, wh[ks], acc[ks & 3]);
            }
        } else {
            if constexpr (XI) acc[0] = unpack4(xv);
#pragma unroll
            for (int ks = 0; ks < 32; ++ks) {
                const float* p = h0 + ks * 32 + lk * 8;
                s16x8 a = pack8(*(const f32x4*)p, *(const f32x4*)(p + 4), KEEP);
                acc[ks & 3] = MFMA(a, wh[ks], acc[ks & 3]);
            }
        }

        f32x4 r4 = (acc[0] + acc[1]) + (acc[2] + acc[3]);

        if (s < S_LEN - 1) {
            short* op = hbuf + (size_t)(s & dmask) * BH;
#pragma unroll
            for (int r = 0; r < 4; ++r)
                sth<PURE>(op + (crow + r) * H_SZ + j, f2bf(KEEP * fast_tanh(r4[r])));
            asm volatile("s_waitcnt vmcnt(0)" ::: "memory");
            if (lane < 16) sig_flag<PURE>(fanout);
            if constexpr (XI)
                xv = *(const long*)(xi_lane + (size_t)(s + 1) * (256u * 4 * 64 * 8));
        } else {
#pragma unroll
            for (int r = 0; r < 4; ++r)
                out[(crow + r) * H_SZ + j] = fast_tanh(r4[r]);
        }
    }
}

// -------- fine-grained tile-pipelined step loop (PURE + XI only) --------
// FULLY UNROLLED (R15's #pragma unroll 1 made wh/acc runtime-indexed ->
// scratch spill, VGPR 68, 3.5GB scratch traffic — rule #20). LDS double-
// buffered (2x32KB): staging s never collides with consumption of s-1 ->
// no own-WG guard. stage(i)/consume(i) interleaved: chunk-0 MFMAs overlap
// polls for later producers. No __syncthreads in the hot loop.
template<int XI>
static __device__ __forceinline__ void step_loop_fine(
    const float* __restrict__ h0, float* __restrict__ out,
    short* __restrict__ hbuf, int* __restrict__ flags,
    const char* __restrict__ xi_lane, char* h_lds,
    const s16x8 (&wh)[32],
    int g, int b0, int role, int t, int j, int wIdx, int wave, int lane, int tid,
    int dmask)
{
    const int ln = lane & 15;
    const int lk = lane >> 4;
    const int crow = b0 + lk * 4;
    const int xr = (ln & 7) << 4;
    volatile int* lflag = (volatile int*)(h_lds + 2 * 32768);  // 2 x 16 flags
    int* const inbox  = flags + role * 64;
    int* const fanout = flags + ((g * 16 + lane) * 64 + wIdx);

    const int srow = lane & 15;     // staging row within the 16-row slice
    const int su   = lane >> 4;     // staging 8B-unit base (0..3)
    const int xw   = (srow & 7) << 4;

    if (tid < 32) lflag[tid] = 0;
    __syncthreads();                // once, before the loop

    long xv = 0;
    if constexpr (XI) xv = *(const long*)xi_lane;

#pragma unroll 1
    for (int s = 0; s < S_LEN; ++s) {
        f32x4 acc[4];
        acc[1] = f32x4{ 0.f, 0.f, 0.f, 0.f };
        acc[2] = f32x4{ 0.f, 0.f, 0.f, 0.f };
        acc[3] = f32x4{ 0.f, 0.f, 0.f, 0.f };

        if (s > 0) {
            char* lbuf = h_lds + (s & 1) * 32768;
            volatile int* lf = lflag + (s & 1) * 16;
            const char* slice = (const char*)(hbuf + (size_t)((s - 1) & dmask) * BH
                                              + (size_t)b0 * H_SZ);
            if constexpr (XI) acc[0] = unpack4(xv);
            else              acc[0] = f32x4{ 0.f, 0.f, 0.f, 0.f };

#pragma unroll
            for (int i = 0; i < 4; ++i) {          // i is STATIC after unroll
                const int tp = wave + i * 4;       // runtime: addresses only
                // ---- poll producer tp's 4 wave-slots (L2-local atomics) ----
                int* sp = inbox + tp * 4 + (lane & 3);
                int it = 0;
                for (;;) {
                    int v = (lane < 4) ? rmw_flag<1>(sp, 0) : s;
                    if (__all(v >= s)) break;
                    if (++it > (1 << 14)) break;      // watchdog: fail-visible
                    __builtin_amdgcn_s_sleep(1);
                }
                // ---- stage tile tp (2KB): 4 x 8B per lane, swizzled image ----
                const char* gb = slice + srow * 2048 + tp * 128;
                char* lb = lbuf + tp * 2048 + srow * 128;
#pragma unroll
                for (int q = 0; q < 4; ++q) {
                    const int u = su + q * 4;
                    long v = AGT_LD((const long*)(gb + u * 8));
                    *(long*)(lb + ((u * 8) ^ xw)) = v;
                }
                __threadfence_block();               // LDS data before flag
                if (lane == 0) lf[tp] = s;

                // ---- consume chunk i (tiles 4i..4i+3): STATIC wh/acc idx ----
                int it2 = 0;
                for (;;) {
                    int v = (lane < 4) ? lf[i * 4 + lane] : s;
                    if (__all(v >= s)) break;
                    if (++it2 > (1 << 16)) break;     // watchdog: fail-visible
                }
                __builtin_amdgcn_sched_barrier(0);    // keep reads below spin
#pragma unroll
                for (int t2 = 0; t2 < 4; ++t2) {
                    const int tile = i * 4 + t2;
                    const char* tb = lbuf + tile * 2048 + ln * 128;
#pragma unroll
                    for (int half = 0; half < 2; ++half) {
                        const int ks = tile * 2 + half;
                        s16x8 a = *(const s16x8*)(tb + ((half * 64 + lk * 16) ^ xr));
                        acc[ks & 3] = MFMA(a, wh[ks], acc[ks & 3]);
                    }
                }
            }
        } else {
            if constexpr (XI) acc[0] = unpack4(xv);
            else              acc[0] = f32x4{ 0.f, 0.f, 0.f, 0.f };
            // step 0: h0 broadcast across batch (same fragment for all rows)
#pragma unroll
            for (int ks = 0; ks < 32; ++ks) {
                const float* p = h0 + ks * 32 + lk * 8;
                s16x8 a = pack8(*(const f32x4*)p, *(const f32x4*)(p + 4), KEEP);
                acc[ks & 3] = MFMA(a, wh[ks], acc[ks & 3]);
            }
        }

        f32x4 r4 = (acc[0] + acc[1]) + (acc[2] + acc[3]);

        // producer tail — byte-identical to R14
        if (s < S_LEN - 1) {
            short* op = hbuf + (size_t)(s & dmask) * BH;
#pragma unroll
            for (int r = 0; r < 4; ++r)
                sth<1>(op + (crow + r) * H_SZ + j, f2bf(KEEP * fast_tanh(r4[r])));
            asm volatile("s_waitcnt vmcnt(0)" ::: "memory");
            if (lane < 16) sig_flag<1>(fanout);
            if constexpr (XI)
                xv = *(const long*)(xi_lane + (size_t)(s + 1) * (256u * 4 * 64 * 8));
        } else {
#pragma unroll
            for (int r = 0; r < 4; ++r)
                out[(crow + r) * H_SZ + j] = fast_tanh(r4[r]);
        }
    }
}

// ---------- kernel A: xi = x@Wi^T + b (sync-free; coalesced output) ----------
__global__ __launch_bounds__(256, 1) void xi_gemm(
    const float* __restrict__ x, const float* __restrict__ Wi,
    const float* __restrict__ bias, char* __restrict__ xi)
{
    const int bid  = blockIdx.x;
    const int role = bid & 255;
    const int c    = bid >> 8;
    const int tid  = threadIdx.x;
    const int wave = tid >> 6;
    const int lane = tid & 63;
    const int ln   = lane & 15;
    const int lk   = lane >> 4;

    const int b0    = (role >> 4) * 16;
    const int jtile = (role & 15) * 64;

    s16x8 wia[4][8];
    float b4[4];
#pragma unroll
    for (int jt = 0; jt < 4; ++jt) {
        b4[jt] = bias[jtile + jt * 16 + ln];
#pragma unroll
        for (int kf = 0; kf < 8; ++kf) {
            const float* p = Wi + (size_t)(jtile + jt * 16 + ln) * F_SZ
                           + kf * 32 + lk * 8;
            wia[jt][kf] = pack8_pk(*(const f32x4*)p, *(const f32x4*)(p + 4));
        }
    }

#pragma unroll 1
    for (int i = 0; i < 16; ++i) {
        const int s = c * 64 + wave + 4 * i;
        const float* xp = x + ((size_t)s * B_SZ + b0 + ln) * F_SZ + lk * 8;
        s16x8 af[8];
#pragma unroll
        for (int kf = 0; kf < 8; ++kf)
            af[kf] = pack8_pk(*(const f32x4*)(xp + kf * 32),
                              *(const f32x4*)(xp + kf * 32 + 4));
#pragma unroll
        for (int jt = 0; jt < 4; ++jt) {
            f32x4 a = { b4[jt], b4[jt], b4[jt], b4[jt] };
#pragma unroll
            for (int kf = 0; kf < 8; ++kf)
                a = MFMA(af[kf], wia[jt][kf], a);
            *(long*)(xi + ((((size_t)s * 256 + role) * 4 + jt) * 64 + lane) * 8)
                = pack4_pk(a);
        }
    }
}

// ---------- kernel B: recurrence ----------
template<int XI>
__global__ __launch_bounds__(256, 1) void rnn_fused(
    const float* __restrict__ x, const float* __restrict__ Wi,
    const float* __restrict__ bias, const float* __restrict__ Wh,
    const float* __restrict__ h0, float* __restrict__ out,
    short* __restrict__ hbuf, int* __restrict__ roster, int* __restrict__ flags,
    const char* __restrict__ xi, int dmask)
{
    __shared__ char h_lds[2 * 32768 + 128];   // 2 h-buffers + 2 flag sets
    __shared__ int sh_pure;
    const int bid  = blockIdx.x;
    const int role = ((bid & 7) << 5) | (bid >> 3);
    const int g    = role >> 4;
    const int t    = role & 15;
    const int tid  = threadIdx.x;
    const int wave = tid >> 6;
    const int lane = tid & 63;
    const int ln   = lane & 15;
    const int lk   = lane >> 4;

    int xcc;
    asm volatile("s_getreg_b32 %0, hwreg(HW_REG_XCC_ID)" : "=s"(xcc));
    xcc &= 7;

    if (tid == 0) SYS_ST(&roster[role], xcc + 1);
    if (tid < 16) {
        const int* rp = roster + g * 16 + tid;
        int v, it = 0;
        do { v = SYS_LD(rp); if (v) break; if (++it > (1 << 18)) break;
             __builtin_amdgcn_s_sleep(1); } while (1);
        int p = __all(v == __shfl(v, 0));
        if (tid == 0) sh_pure = p;
    }
    __syncthreads();
    const int pure = sh_pure;

    const int b0 = g * 16;
    const int j  = t * 64 + wave * 16 + ln;
    const int wIdx = t * 4 + wave;
    const char* xi_lane = xi + (((size_t)role * 4 + wave) * 64 + lane) * 8;

    s16x8 wh[32];
#pragma unroll
    for (int ks = 0; ks < 32; ++ks) {
        const float* p = Wh + (size_t)j * H_SZ + ks * 32 + lk * 8;
        wh[ks] = pack8(*(const f32x4*)p, *(const f32x4*)(p + 4), 1.0f);
    }
    s16x8 wif[8];
    if constexpr (!XI) {
#pragma unroll
        for (int kf = 0; kf < 8; ++kf) {
            const float* p = Wi + (size_t)j * F_SZ + kf * 32 + lk * 8;
            wif[kf] = pack8(*(const f32x4*)p, *(const f32x4*)(p + 4), 1.0f);
        }
    } else {
#pragma unroll
        for (int kf = 0; kf < 8; ++kf) wif[kf] = s16x8{0,0,0,0,0,0,0,0};
    }
    const float bj = XI ? 0.f : bias[j];

    if (pure && XI) {
        step_loop_fine<XI>(h0, out, hbuf, flags, xi_lane, h_lds, wh,
                           g, b0, role, t, j, wIdx, wave, lane, tid, dmask);
    } else if (pure) {
        step_loop<1, XI>(x, h0, out, hbuf, flags, xi_lane, h_lds, wh, wif, bj,
                         g, b0, role, j, wIdx, wave, lane, tid, dmask);
    } else {
        step_loop<0, XI>(x, h0, out, hbuf, flags, xi_lane, h_lds, wh, wif, bj,
                         g, b0, role, j, wIdx, wave, lane, tid, dmask);
    }
}

extern "C" void kernel_launch(void* const* d_in, const int* in_sizes, int n_in,
                              void* d_out, int out_size, void* d_ws, size_t ws_size,
                              hipStream_t stream) {
    const float* x  = (const float*)d_in[0];
    const float* Wi = (const float*)d_in[1];
    const float* bi = (const float*)d_in[2];
    const float* Wh = (const float*)d_in[3];
    const float* h0 = (const float*)d_in[4];
    float* out = (float*)d_out;

    int*   roster = (int*)d_ws;                          // 256 ints @ 0
    int*   flags  = (int*)((char*)d_ws + (4 << 10));     // 256 inboxes x 64 = 64KB
    short* hbuf   = (short*)((char*)d_ws + (128 << 10)); // depth x 512 KB bf16
    char*  xi     = (char*)d_ws + (128 << 10) + 4 * (size_t)BH * 2;

    const size_t need4   = (128u << 10) + 4 * (size_t)BH * 2;          // ~2.1 MB
    const size_t need_xi = need4 + (size_t)S_LEN * 256 * 4 * 64 * 8;   // ~270.7 MB

    const int dmask = (ws_size >= need4) ? 3 : 1;

    // roster + inboxes MUST be zero every call (graph replays don't re-poison)
    (void)hipMemsetAsync(d_ws, 0, (68 << 10), stream);

    if (ws_size >= need_xi) {
        xi_gemm<<<dim3(2048), dim3(256), 0, stream>>>(x, Wi, bi, xi);
        rnn_fused<1><<<dim3(256), dim3(256), 0, stream>>>(
            x, Wi, bi, Wh, h0, out, hbuf, roster, flags, xi, dmask);
    } else {
        rnn_fused<0><<<dim3(256), dim3(256), 0, stream>>>(
            x, Wi, bi, Wh, h0, out, hbuf, roster, flags, nullptr, dmask);
    }
}